// Round 8
// baseline (754.960 us; speedup 1.0000x reference)
//
#include <hip/hip_runtime.h>

#define MM 2048     // memory slots
#define BB 64       // batch
#define TT 4        // tokens per slot
#define DD 128      // embed dim
#define VV 50000    // vocab
#define VPAD 50176  // VV rounded up to multiple of 256

typedef float f4v __attribute__((ext_vector_type(4)));
typedef short s8v __attribute__((ext_vector_type(8)));

// float -> bf16 bits (RNE)
__device__ __forceinline__ unsigned short f2bf(float f) {
    unsigned int u = __float_as_uint(f);
    u = u + 0x7FFFu + ((u >> 16) & 1u);
    return (unsigned short)(u >> 16);
}

// ---- init: zero u (2048 f4) + W (802816 f4), contiguous ----
__global__ __launch_bounds__(256) void k_init(float4* __restrict__ p) {
    p[blockIdx.x * 256 + threadIdx.x] = make_float4(0.f, 0.f, 0.f, 0.f);
}

// ---- hop-0 scatter: W[tok*64+b] += 1/2048 (uniform softmax, exact) ----
__global__ __launch_bounds__(256) void k_scatter0(const int* __restrict__ st,
                                                  float* __restrict__ W) {
    const int g = blockIdx.x * 256 + threadIdx.x;  // g = m*64+b
    const int b = g & 63;
    const int4 tk = ((const int4*)st)[g];
    const float p = 1.0f / 2048.0f;
    if (tk.x) atomicAdd(W + (size_t)tk.x * 64 + b, p);
    if (tk.y) atomicAdd(W + (size_t)tk.y * 64 + b, p);
    if (tk.z) atomicAdd(W + (size_t)tk.z * 64 + b, p);
    if (tk.w) atomicAdd(W + (size_t)tk.w * 64 + b, p);
}

// ---- GEMM1 (MFMA bf16): P[v][b] = dot(C[h][v][:], u[b][:]) ----
// Prologue: zero this block's W slice (1024 f4); blocks 0..7 optionally seed
// d_out with u (hop 2). Body identical to validated round-7 kernel.
__global__ __launch_bounds__(256, 4) void k_gemm_p(const float* __restrict__ Ch,
                                                   const float* __restrict__ u,
                                                   float* __restrict__ P,
                                                   float4* __restrict__ Wz,
                                                   float4* __restrict__ dseed) {
    __shared__ short lds[128 * 136];  // 34.8 KB bf16
    const int t = threadIdx.x;
    const int v0 = blockIdx.x * 64;

    {   // zero W slice: VPAD*64/4 = 802816 f4 over 784 blocks = 1024 each
        const float4 z = make_float4(0.f, 0.f, 0.f, 0.f);
        const int base = blockIdx.x * 1024 + t;
        Wz[base] = z; Wz[base + 256] = z; Wz[base + 512] = z; Wz[base + 768] = z;
    }
    if (dseed && blockIdx.x < 8) {  // seed d_out = u (8192 f = 2048 f4)
        const int i = blockIdx.x * 256 + t;
        dseed[i] = ((const float4*)u)[i];
    }

    // stage: 128 rows x 128 floats -> bf16. coalesced float4 loads.
#pragma unroll
    for (int i = 0; i < 16; ++i) {
        const int G = i * 256 + t;        // f4-index
        const int row = G >> 5;           // 0..127
        const int c4 = G & 31;            // f4 within row
        float4 val;
        if (row < 64) {
            const int v = v0 + row;
            val = (v < VV) ? *(const float4*)(Ch + (size_t)v * DD + c4 * 4)
                           : make_float4(0.f, 0.f, 0.f, 0.f);
        } else {
            val = *(const float4*)(u + (size_t)(row - 64) * DD + c4 * 4);
        }
        const unsigned int lo = ((unsigned int)f2bf(val.y) << 16) | f2bf(val.x);
        const unsigned int hi = ((unsigned int)f2bf(val.w) << 16) | f2bf(val.z);
        *(uint2*)(lds + row * 136 + c4 * 4) = make_uint2(lo, hi);
    }
    __syncthreads();

    const int l = t & 63;
    const int w = t >> 6;       // wave id 0..3
    const int quad = l >> 4;    // 0..3
    const int n16 = l & 15;

    const int arow = (16 * w + n16) * 136;
    const int brow0 = (64 + 0 * 16 + n16) * 136;
    const int brow1 = (64 + 1 * 16 + n16) * 136;
    const int brow2 = (64 + 2 * 16 + n16) * 136;
    const int brow3 = (64 + 3 * 16 + n16) * 136;

    f4v ac0 = {0.f, 0.f, 0.f, 0.f}, ac1 = ac0, ac2 = ac0, ac3 = ac0;

#pragma unroll
    for (int s = 0; s < 4; ++s) {
        const int ko = s * 32 + quad * 8;
        const s8v av = *(const s8v*)(lds + arow + ko);
        const s8v b0 = *(const s8v*)(lds + brow0 + ko);
        const s8v b1 = *(const s8v*)(lds + brow1 + ko);
        const s8v b2 = *(const s8v*)(lds + brow2 + ko);
        const s8v b3 = *(const s8v*)(lds + brow3 + ko);
        ac0 = __builtin_amdgcn_mfma_f32_16x16x32_bf16(av, b0, ac0, 0, 0, 0);
        ac1 = __builtin_amdgcn_mfma_f32_16x16x32_bf16(av, b1, ac1, 0, 0, 0);
        ac2 = __builtin_amdgcn_mfma_f32_16x16x32_bf16(av, b2, ac2, 0, 0, 0);
        ac3 = __builtin_amdgcn_mfma_f32_16x16x32_bf16(av, b3, ac3, 0, 0, 0);
    }

    // D layout: n = lane&15, m = quad*4 + reg
    const int vbase = v0 + 16 * w + quad * 4;
#pragma unroll
    for (int r = 0; r < 4; ++r) {
        float* __restrict__ Pr = P + (size_t)(vbase + r) * 64 + n16;
        Pr[0]  = ac0[r];
        Pr[16] = ac1[r];
        Pr[32] = ac2[r];
        Pr[48] = ac3[r];
    }
}

// ---- fused gather + softmax + scatter: one block per b, 1024 thr ----
// thread handles m = tid and m+1024: gather score from P, block softmax,
// scatter prob into W (atomics; zero cross-block contention since b unique).
__global__ __launch_bounds__(1024) void k_gsm(const int* __restrict__ st,
                                              const float* __restrict__ P,
                                              float* __restrict__ W) {
    __shared__ float red[16];
    const int b = blockIdx.x;
    const int tid = threadIdx.x;
    const int4* st4 = (const int4*)st;

    const int4 t0 = st4[(size_t)tid * 64 + b];
    const int4 t1 = st4[(size_t)(tid + 1024) * 64 + b];

    float p0 = 0.f, p1 = 0.f;
    if (t0.x) p0 += P[(size_t)t0.x * 64 + b];
    if (t0.y) p0 += P[(size_t)t0.y * 64 + b];
    if (t0.z) p0 += P[(size_t)t0.z * 64 + b];
    if (t0.w) p0 += P[(size_t)t0.w * 64 + b];
    if (t1.x) p1 += P[(size_t)t1.x * 64 + b];
    if (t1.y) p1 += P[(size_t)t1.y * 64 + b];
    if (t1.z) p1 += P[(size_t)t1.z * 64 + b];
    if (t1.w) p1 += P[(size_t)t1.w * 64 + b];

    // block max
    float mx = fmaxf(p0, p1);
#pragma unroll
    for (int off = 32; off; off >>= 1) mx = fmaxf(mx, __shfl_xor(mx, off, 64));
    if ((tid & 63) == 0) red[tid >> 6] = mx;
    __syncthreads();
    float gmax = red[0];
#pragma unroll
    for (int i = 1; i < 16; ++i) gmax = fmaxf(gmax, red[i]);
    __syncthreads();

    // block sum of exp
    const float e0 = __expf(p0 - gmax);
    const float e1 = __expf(p1 - gmax);
    float sum = e0 + e1;
#pragma unroll
    for (int off = 32; off; off >>= 1) sum += __shfl_xor(sum, off, 64);
    if ((tid & 63) == 0) red[tid >> 6] = sum;
    __syncthreads();
    float tot = red[0];
#pragma unroll
    for (int i = 1; i < 16; ++i) tot += red[i];
    const float inv = 1.f / tot;

    const float pr0 = e0 * inv;
    const float pr1 = e1 * inv;
    if (t0.x) atomicAdd(W + (size_t)t0.x * 64 + b, pr0);
    if (t0.y) atomicAdd(W + (size_t)t0.y * 64 + b, pr0);
    if (t0.z) atomicAdd(W + (size_t)t0.z * 64 + b, pr0);
    if (t0.w) atomicAdd(W + (size_t)t0.w * 64 + b, pr0);
    if (t1.x) atomicAdd(W + (size_t)t1.x * 64 + b, pr1);
    if (t1.y) atomicAdd(W + (size_t)t1.y * 64 + b, pr1);
    if (t1.z) atomicAdd(W + (size_t)t1.z * 64 + b, pr1);
    if (t1.w) atomicAdd(W + (size_t)t1.w * 64 + b, pr1);
}

// ---- GEMM2 (fp32 tiled): out[b][d] += sum_v W[v][b] * C2[v][d] ----
// 128-v slice per block, thread tile 8b x 8d, named accumulators.
// Epilogue: k-group 1 partials combined via LDS, then direct atomicAdd
// into out (u or d_out) -- no partial buffer, no reduce kernel.
__global__ __launch_bounds__(256, 3) void k_gemm_o(const float* __restrict__ C2,
                                                   const float* __restrict__ W,
                                                   float* __restrict__ out) {
    __shared__ float Wl[64 * 68];    // 17.4 KB
    __shared__ float Cl[64 * 136];   // 34.8 KB (= 128*68, reused in epilogue)
    const int t = threadIdx.x;
    const int g = t >> 7;            // k-group
    const int b0 = ((t >> 4) & 7) * 8;
    const int d0 = (t & 15) * 8;
    const int vb = blockIdx.x * 128;

    f4v a0l = {0.f, 0.f, 0.f, 0.f}, a0h = a0l, a1l = a0l, a1h = a0l;
    f4v a2l = a0l, a2h = a0l, a3l = a0l, a3h = a0l;
    f4v a4l = a0l, a4h = a0l, a5l = a0l, a5h = a0l;
    f4v a6l = a0l, a6h = a0l, a7l = a0l, a7h = a0l;

    for (int cc = 0; cc < 2; ++cc) {
        const int vc = vb + cc * 64;
#pragma unroll
        for (int i = 0; i < 4; ++i) {
            const int G = i * 256 + t;
            const int row = G >> 4, c4 = G & 15;
            *(float4*)&Wl[row * 68 + c4 * 4] =
                *(const float4*)(W + (size_t)(vc + row) * 64 + c4 * 4);
        }
#pragma unroll
        for (int i = 0; i < 8; ++i) {
            const int G = i * 256 + t;
            const int row = G >> 5, c4 = G & 31;
            const int v = vc + row;
            float4 val = (v < VV) ? *(const float4*)(C2 + (size_t)v * DD + c4 * 4)
                                  : make_float4(0.f, 0.f, 0.f, 0.f);
            *(float4*)&Cl[row * 136 + c4 * 4] = val;
        }
        __syncthreads();

#define FMA_ROW(al, ah, wc)            \
    al += wc * cA; ah += wc * cB;

#pragma unroll
        for (int j = 0; j < 32; ++j) {
            const int kk = g * 32 + j;
            const f4v wA = *(const f4v*)&Wl[kk * 68 + b0];
            const f4v wB = *(const f4v*)&Wl[kk * 68 + b0 + 4];
            const f4v cA = *(const f4v*)&Cl[kk * 136 + d0];
            const f4v cB = *(const f4v*)&Cl[kk * 136 + d0 + 4];
            FMA_ROW(a0l, a0h, wA[0]) FMA_ROW(a1l, a1h, wA[1])
            FMA_ROW(a2l, a2h, wA[2]) FMA_ROW(a3l, a3h, wA[3])
            FMA_ROW(a4l, a4h, wB[0]) FMA_ROW(a5l, a5h, wB[1])
            FMA_ROW(a6l, a6h, wB[2]) FMA_ROW(a7l, a7h, wB[3])
        }
#undef FMA_ROW
        __syncthreads();
    }

    // combine k-group 1 into k-group 0 via LDS (Cl region: 128*68 = 8704 f)
    const int slot = t & 127;
    float* __restrict__ xb = &Cl[slot * 68];
    if (g == 1) {
        *(f4v*)(xb + 0)  = a0l; *(f4v*)(xb + 4)  = a0h;
        *(f4v*)(xb + 8)  = a1l; *(f4v*)(xb + 12) = a1h;
        *(f4v*)(xb + 16) = a2l; *(f4v*)(xb + 20) = a2h;
        *(f4v*)(xb + 24) = a3l; *(f4v*)(xb + 28) = a3h;
        *(f4v*)(xb + 32) = a4l; *(f4v*)(xb + 36) = a4h;
        *(f4v*)(xb + 40) = a5l; *(f4v*)(xb + 44) = a5h;
        *(f4v*)(xb + 48) = a6l; *(f4v*)(xb + 52) = a6h;
        *(f4v*)(xb + 56) = a7l; *(f4v*)(xb + 60) = a7h;
    }
    __syncthreads();
    if (g == 0) {
        a0l += *(const f4v*)(xb + 0);  a0h += *(const f4v*)(xb + 4);
        a1l += *(const f4v*)(xb + 8);  a1h += *(const f4v*)(xb + 12);
        a2l += *(const f4v*)(xb + 16); a2h += *(const f4v*)(xb + 20);
        a3l += *(const f4v*)(xb + 24); a3h += *(const f4v*)(xb + 28);
        a4l += *(const f4v*)(xb + 32); a4h += *(const f4v*)(xb + 36);
        a5l += *(const f4v*)(xb + 40); a5h += *(const f4v*)(xb + 44);
        a6l += *(const f4v*)(xb + 48); a6h += *(const f4v*)(xb + 52);
        a7l += *(const f4v*)(xb + 56); a7h += *(const f4v*)(xb + 60);
#define AT_ROW(i, al, ah)                                   \
    {                                                       \
        float* __restrict__ o = out + (b0 + i) * DD + d0;   \
        atomicAdd(o + 0, al[0]); atomicAdd(o + 1, al[1]);   \
        atomicAdd(o + 2, al[2]); atomicAdd(o + 3, al[3]);   \
        atomicAdd(o + 4, ah[0]); atomicAdd(o + 5, ah[1]);   \
        atomicAdd(o + 6, ah[2]); atomicAdd(o + 7, ah[3]);   \
    }
        AT_ROW(0, a0l, a0h) AT_ROW(1, a1l, a1h) AT_ROW(2, a2l, a2h)
        AT_ROW(3, a3l, a3h) AT_ROW(4, a4l, a4h) AT_ROW(5, a5l, a5h)
        AT_ROW(6, a6l, a6h) AT_ROW(7, a7l, a7h)
#undef AT_ROW
    }
}

extern "C" void kernel_launch(void* const* d_in, const int* in_sizes, int n_in,
                              void* d_out, int out_size, void* d_ws, size_t ws_size,
                              hipStream_t stream) {
    const int* st = (const int*)d_in[0];
    const float* C = (const float*)d_in[1];
    float* dout = (float*)d_out;

    float* u = (float*)d_ws;             // 8192 f, layout [b][d]
    float* W = u + BB * DD;              // VPAD*64 f = 12.85 MB (contig w/ u)
    float* P = W + (size_t)VPAD * BB;    // VPAD*64 f = 12.85 MB

    const float* C1 = C + (size_t)1 * VV * DD;
    const float* C2 = C + (size_t)2 * VV * DD;
    const float* C3 = C + (size_t)3 * VV * DD;

    // 1. zero u + W (contiguous: 804864 f4)
    k_init<<<3144, 256, 0, stream>>>((float4*)d_ws);
    // 2. hop 0: uniform softmax -> count scatter (exact)
    k_scatter0<<<512, 256, 0, stream>>>(st, W);
    // 3. hop 0 output: u += W^T C1
    k_gemm_o<<<VPAD / 128, 256, 0, stream>>>(C1, W, u);
    // 4. hop 1 scores (+ re-zero W)
    k_gemm_p<<<VPAD / 64, 256, 0, stream>>>(C1, u, P, (float4*)W, nullptr);
    // 5. hop 1 softmax + scatter
    k_gsm<<<BB, 1024, 0, stream>>>(st, P, W);
    // 6. hop 1 output: u += W^T C2
    k_gemm_o<<<VPAD / 128, 256, 0, stream>>>(C2, W, u);
    // 7. hop 2 scores (+ re-zero W, + seed d_out = u)
    k_gemm_p<<<VPAD / 64, 256, 0, stream>>>(C2, u, P, (float4*)W, (float4*)dout);
    // 8. hop 2 softmax + scatter
    k_gsm<<<BB, 1024, 0, stream>>>(st, P, W);
    // 9. hop 2 output straight into d_out
    k_gemm_o<<<VPAD / 128, 256, 0, stream>>>(C3, W, dout);
}